// Round 5
// baseline (286.611 us; speedup 1.0000x reference)
//
#include <hip/hip_runtime.h>
#include <hip/hip_bf16.h>

constexpr int NPIX = 4096;   // H*W
constexpr int NB   = 2;      // batch
constexpr int MS   = 2;      // m-split for attention
constexpr int QB   = 32;     // queries per attention block
constexpr int TM   = 64;     // m per wave-iteration
constexpr int PPITCH = 72;   // P_lds row pitch (bf16): 2-way bank alias only (free)

typedef __attribute__((ext_vector_type(8))) short bf16x8;
typedef __attribute__((ext_vector_type(4))) float f32x4;

// ---------------------------------------------------------------------------
// conv1x1 fp32 + fused BN partial stats.
// CPT output channels x 4 pixels per thread. grid = (4, Co/CPT, NB).
// Writes y and per-block channel sum/sumsq partials (8 deterministic partials).
// ---------------------------------------------------------------------------
template <int CPT>
__global__ __launch_bounds__(256) void conv_stats_k(
    const float* __restrict__ x, const float* __restrict__ w,
    const float* __restrict__ bias, float* __restrict__ y,
    float* __restrict__ psum, float* __restrict__ psq, int Ci, int Co) {
  const int t  = threadIdx.x;
  const int n  = (blockIdx.x * 256 + t) * 4;
  const int d0 = blockIdx.y * CPT;
  const int b  = blockIdx.z;
  float4 a[CPT];
#pragma unroll
  for (int j = 0; j < CPT; ++j) {
    float bv = bias ? bias[d0 + j] : 0.f;
    a[j] = float4{bv, bv, bv, bv};
  }
  const float* xb = x + ((size_t)b * Ci) * NPIX + n;
  const float* wr = w + d0;
  for (int c = 0; c < Ci; ++c) {
    float4 xv = *(const float4*)(xb + (size_t)c * NPIX);
#pragma unroll
    for (int j = 0; j < CPT; ++j) {
      float wj = wr[j];
      a[j].x += xv.x * wj; a[j].y += xv.y * wj;
      a[j].z += xv.z * wj; a[j].w += xv.w * wj;
    }
    wr += Co;
  }
  float* yb = y + ((size_t)b * Co + d0) * NPIX + n;
#pragma unroll
  for (int j = 0; j < CPT; ++j) *(float4*)(yb + (size_t)j * NPIX) = a[j];

  // per-thread channel sums
  float s[CPT], s2[CPT];
#pragma unroll
  for (int j = 0; j < CPT; ++j) {
    s[j]  = (a[j].x + a[j].y) + (a[j].z + a[j].w);
    s2[j] = (a[j].x * a[j].x + a[j].y * a[j].y) + (a[j].z * a[j].z + a[j].w * a[j].w);
  }
  // wave butterfly reduce
#pragma unroll
  for (int j = 0; j < CPT; ++j) {
    for (int d = 1; d < 64; d <<= 1) {
      s[j]  += __shfl_xor(s[j], d);
      s2[j] += __shfl_xor(s2[j], d);
    }
  }
  __shared__ float shA[4][CPT];
  __shared__ float shB[4][CPT];
  const int wave = t >> 6, lane = t & 63;
  if (lane == 0) {
#pragma unroll
    for (int j = 0; j < CPT; ++j) { shA[wave][j] = s[j]; shB[wave][j] = s2[j]; }
  }
  __syncthreads();
  if (t < CPT) {
    const int p = b * 4 + blockIdx.x;   // 8 partials per channel
    psum[(size_t)(d0 + t) * 8 + p] = (shA[0][t] + shA[1][t]) + (shA[2][t] + shA[3][t]);
    psq [(size_t)(d0 + t) * 8 + p] = (shB[0][t] + shB[1][t]) + (shB[2][t] + shB[3][t]);
  }
}

// ---------------------------------------------------------------------------
// BN finalize: per-channel fused affine sc = rstd*g, sb = bb - mean*sc
// ---------------------------------------------------------------------------
__global__ __launch_bounds__(256) void bn_finalize_k(
    const float* __restrict__ psum, const float* __restrict__ psq,
    const float* __restrict__ g, const float* __restrict__ bb,
    float* __restrict__ sc, float* __restrict__ sb, int C) {
  int c = blockIdx.x * 256 + threadIdx.x;
  if (c >= C) return;
  float s = 0.f, s2 = 0.f;
#pragma unroll
  for (int p = 0; p < 8; ++p) { s += psum[(size_t)c * 8 + p]; s2 += psq[(size_t)c * 8 + p]; }
  const float inv = 1.f / (NB * NPIX);
  float m = s * inv;
  float var = s2 * inv - m * m;
  float r = rsqrtf(var + 1e-5f) * g[c];
  sc[c] = r;
  sb[c] = bb[c] - m * r;
}

// ---------------------------------------------------------------------------
// f & g convs fused, BN+ReLU applied on the fly from y.
// Output transposed + channel-padded to 32: [B][N][32] bf16.
// ---------------------------------------------------------------------------
template <int CF>
__global__ __launch_bounds__(256) void fg_convT_k(
    const float* __restrict__ y, const float* __restrict__ scv, const float* __restrict__ sbv,
    const float* __restrict__ wf, const float* __restrict__ bfv,
    const float* __restrict__ wg, const float* __restrict__ bgv,
    __hip_bfloat16* __restrict__ fqT, __hip_bfloat16* __restrict__ gqT, int Ci) {
  int n = blockIdx.x * 256 + threadIdx.x;
  int b = blockIdx.y;
  float fa[CF], ga[CF];
#pragma unroll
  for (int j = 0; j < CF; ++j) { fa[j] = bfv[j]; ga[j] = bgv[j]; }
  const float* xb = y + ((size_t)b * Ci) * NPIX + n;
  for (int ci = 0; ci < Ci; ci += 4) {
    float x0 = fmaxf(xb[(size_t)(ci + 0) * NPIX] * scv[ci + 0] + sbv[ci + 0], 0.f);
    float x1 = fmaxf(xb[(size_t)(ci + 1) * NPIX] * scv[ci + 1] + sbv[ci + 1], 0.f);
    float x2 = fmaxf(xb[(size_t)(ci + 2) * NPIX] * scv[ci + 2] + sbv[ci + 2], 0.f);
    float x3 = fmaxf(xb[(size_t)(ci + 3) * NPIX] * scv[ci + 3] + sbv[ci + 3], 0.f);
#pragma unroll
    for (int j = 0; j < CF; ++j) {
      fa[j] += x0 * wf[(size_t)(ci + 0) * CF + j] + x1 * wf[(size_t)(ci + 1) * CF + j] +
               x2 * wf[(size_t)(ci + 2) * CF + j] + x3 * wf[(size_t)(ci + 3) * CF + j];
      ga[j] += x0 * wg[(size_t)(ci + 0) * CF + j] + x1 * wg[(size_t)(ci + 1) * CF + j] +
               x2 * wg[(size_t)(ci + 2) * CF + j] + x3 * wg[(size_t)(ci + 3) * CF + j];
    }
  }
  __align__(16) __hip_bfloat16 of[32];
  __align__(16) __hip_bfloat16 og[32];
#pragma unroll
  for (int j = 0; j < 32; ++j) {
    of[j] = __float2bfloat16(j < CF ? fa[j] : 0.f);
    og[j] = __float2bfloat16(j < CF ? ga[j] : 0.f);
  }
  uint4* df = (uint4*)(fqT + ((size_t)b * NPIX + n) * 32);
  uint4* dg = (uint4*)(gqT + ((size_t)b * NPIX + n) * 32);
#pragma unroll
  for (int k = 0; k < 4; ++k) { df[k] = ((uint4*)of)[k]; dg[k] = ((uint4*)og)[k]; }
}

// ---------------------------------------------------------------------------
// h conv -> bf16, BN+ReLU on the fly. 4 pixels x 4 channels per thread.
// ---------------------------------------------------------------------------
__global__ __launch_bounds__(256) void conv_bf16_k(
    const float* __restrict__ y, const float* __restrict__ scv, const float* __restrict__ sbv,
    const float* __restrict__ w, const float* __restrict__ bias,
    __hip_bfloat16* __restrict__ out, int Ci, int Co) {
  int n  = (blockIdx.x * 256 + threadIdx.x) * 4;
  int d0 = blockIdx.y * 4;
  int b  = blockIdx.z;
  float bv0 = bias[d0], bv1 = bias[d0 + 1], bv2 = bias[d0 + 2], bv3 = bias[d0 + 3];
  float4 a0 = {bv0, bv0, bv0, bv0};
  float4 a1 = {bv1, bv1, bv1, bv1};
  float4 a2 = {bv2, bv2, bv2, bv2};
  float4 a3 = {bv3, bv3, bv3, bv3};
  const float* xb = y + ((size_t)b * Ci) * NPIX + n;
  const float* wr = w + d0;
#pragma unroll 2
  for (int c = 0; c < Ci; ++c) {
    float4 xv = *(const float4*)(xb + (size_t)c * NPIX);
    float s = scv[c], o = sbv[c];
    xv.x = fmaxf(xv.x * s + o, 0.f);
    xv.y = fmaxf(xv.y * s + o, 0.f);
    xv.z = fmaxf(xv.z * s + o, 0.f);
    xv.w = fmaxf(xv.w * s + o, 0.f);
    float w0 = wr[0], w1 = wr[1], w2 = wr[2], w3 = wr[3];
    a0.x += xv.x * w0; a0.y += xv.y * w0; a0.z += xv.z * w0; a0.w += xv.w * w0;
    a1.x += xv.x * w1; a1.y += xv.y * w1; a1.z += xv.z * w1; a1.w += xv.w * w1;
    a2.x += xv.x * w2; a2.y += xv.y * w2; a2.z += xv.z * w2; a2.w += xv.w * w2;
    a3.x += xv.x * w3; a3.y += xv.y * w3; a3.z += xv.z * w3; a3.w += xv.w * w3;
    wr += Co;
  }
  __hip_bfloat16* yb = out + ((size_t)b * Co + d0) * NPIX + n;
  auto st4 = [](__hip_bfloat16* p, float4 v) {
    __hip_bfloat162 lo, hi;
    lo.x = __float2bfloat16(v.x); lo.y = __float2bfloat16(v.y);
    hi.x = __float2bfloat16(v.z); hi.y = __float2bfloat16(v.w);
    uint2 u; u.x = *(unsigned*)&lo; u.y = *(unsigned*)&hi;
    *(uint2*)p = u;
  };
  st4(yb, a0);
  st4(yb + NPIX, a1);
  st4(yb + 2 * (size_t)NPIX, a2);
  st4(yb + 3 * (size_t)NPIX, a3);
}

// ---------------------------------------------------------------------------
// MFMA flash attention partial. pacc layout [MS][B][CO][N].
// ---------------------------------------------------------------------------
template <int CO>
__global__ __launch_bounds__(256, 2) void attn_mfma_k(
    const __hip_bfloat16* __restrict__ fqT, const __hip_bfloat16* __restrict__ gqT,
    const __hip_bfloat16* __restrict__ hq,
    float* __restrict__ pacc, float* __restrict__ pl) {
  constexpr int CSUB   = CO / 16;
  constexpr int OPITCH = CO + 1;
  constexpr int PBYTES = 4 * QB * PPITCH * 2;
  constexpr int OBYTES = 4 * QB * OPITCH * 4;
  constexpr int SBYTES = PBYTES > OBYTES ? PBYTES : OBYTES;
  __shared__ __align__(16) char smem[SBYTES];
  __shared__ float l_red[4][QB];
  unsigned short* Pw = (unsigned short*)smem;
  float* Ored = (float*)smem;

  const int t = threadIdx.x;
  const int wave = t >> 6, lane = t & 63, lq = lane & 15, lg = lane >> 4;
  const int qblk = blockIdx.x, ms = blockIdx.y, b = blockIdx.z;
  const int q0 = qblk * QB;

  bf16x8 ff[2];
#pragma unroll
  for (int qs = 0; qs < 2; ++qs)
    ff[qs] = *reinterpret_cast<const bf16x8*>(
        fqT + (((size_t)b * NPIX + q0 + qs * 16 + lq) << 5) + lg * 8);

  f32x4 acc[2][CSUB];
#pragma unroll
  for (int qs = 0; qs < 2; ++qs)
#pragma unroll
    for (int cs = 0; cs < CSUB; ++cs) acc[qs][cs] = f32x4{0.f, 0.f, 0.f, 0.f};
  float ls[2] = {0.f, 0.f};

  unsigned short* Pmy = Pw + wave * QB * PPITCH;
  const __hip_bfloat16* hbase = hq + ((size_t)b * CO + lq) * NPIX + lg * 8;

  const int mbeg = ms * (NPIX / MS) + wave * TM;
  const int mend = (ms + 1) * (NPIX / MS);
  for (int mt = mbeg; mt < mend; mt += 4 * TM) {
#pragma unroll
    for (int msub = 0; msub < 4; ++msub) {
      bf16x8 ga = *reinterpret_cast<const bf16x8*>(
          gqT + (((size_t)b * NPIX + mt + msub * 16 + lq) << 5) + lg * 8);
#pragma unroll
      for (int qs = 0; qs < 2; ++qs) {
        f32x4 z = {0.f, 0.f, 0.f, 0.f};
        f32x4 S = __builtin_amdgcn_mfma_f32_16x16x32_bf16(ga, ff[qs], z, 0, 0, 0);
        float p0 = __expf(fminf(S[0], 60.f));
        float p1 = __expf(fminf(S[1], 60.f));
        float p2 = __expf(fminf(S[2], 60.f));
        float p3 = __expf(fminf(S[3], 60.f));
        ls[qs] += (p0 + p1) + (p2 + p3);
        __hip_bfloat162 t0, t1;
        t0.x = __float2bfloat16(p0); t0.y = __float2bfloat16(p1);
        t1.x = __float2bfloat16(p2); t1.y = __float2bfloat16(p3);
        uint2 wv;
        wv.x = *(unsigned*)&t0; wv.y = *(unsigned*)&t1;
        *(uint2*)(Pmy + (qs * 16 + lq) * PPITCH + msub * 16 + lg * 4) = wv;
      }
    }
#pragma unroll
    for (int kc = 0; kc < 2; ++kc) {
      bf16x8 pa[2];
#pragma unroll
      for (int qs = 0; qs < 2; ++qs)
        pa[qs] = *reinterpret_cast<const bf16x8*>(
            Pmy + (qs * 16 + lq) * PPITCH + kc * 32 + lg * 8);
      const __hip_bfloat16* hp = hbase + mt + kc * 32;
#pragma unroll
      for (int cs = 0; cs < CSUB; ++cs) {
        bf16x8 hv = *reinterpret_cast<const bf16x8*>(hp + (size_t)cs * 16 * NPIX);
#pragma unroll
        for (int qs = 0; qs < 2; ++qs)
          acc[qs][cs] = __builtin_amdgcn_mfma_f32_16x16x32_bf16(pa[qs], hv, acc[qs][cs], 0, 0, 0);
      }
    }
  }

#pragma unroll
  for (int qs = 0; qs < 2; ++qs) {
    float l = ls[qs];
    l += __shfl_xor(l, 16);
    l += __shfl_xor(l, 32);
    ls[qs] = l;
  }

  __syncthreads();
  if (lane < 16) { l_red[wave][lq] = ls[0]; l_red[wave][16 + lq] = ls[1]; }
#pragma unroll
  for (int qs = 0; qs < 2; ++qs)
#pragma unroll
    for (int cs = 0; cs < CSUB; ++cs)
#pragma unroll
      for (int r = 0; r < 4; ++r)
        Ored[((size_t)wave * QB + qs * 16 + 4 * lg + r) * OPITCH + cs * 16 + lq] = acc[qs][cs][r];
  __syncthreads();

  const size_t obase = (((size_t)ms * NB + b) * CO) * NPIX + q0;
  for (int e = t; e < QB * CO; e += 256) {
    int c = e >> 5;
    int q = e & 31;
    float o = Ored[((size_t)0 * QB + q) * OPITCH + c] + Ored[((size_t)1 * QB + q) * OPITCH + c] +
              Ored[((size_t)2 * QB + q) * OPITCH + c] + Ored[((size_t)3 * QB + q) * OPITCH + c];
    pacc[obase + (size_t)c * NPIX + q] = o;
  }
  if (t < QB) {
    pl[((size_t)ms * NB + b) * NPIX + q0 + t] =
        l_red[0][t] + l_red[1][t] + l_red[2][t] + l_red[3][t];
  }
}

// ---------------------------------------------------------------------------
// Attention combine: merge m-splits, normalize, gamma + residual (BN+ReLU of y
// applied on the fly). float4 streaming.
// ---------------------------------------------------------------------------
template <int CO>
__global__ __launch_bounds__(256) void attn_combine2_k(
    const float* __restrict__ pacc, const float* __restrict__ pl,
    const float* __restrict__ y, const float* __restrict__ scv, const float* __restrict__ sbv,
    const float* __restrict__ gam, float* __restrict__ xout) {
  int i4 = blockIdx.x * 256 + threadIdx.x;   // over NB*CO*NPIX/4
  int n  = (i4 & 1023) * 4;
  int bc = i4 >> 10;
  int b  = bc / CO, c = bc - b * CO;
  float4 o = {0.f, 0.f, 0.f, 0.f};
  float4 L = {0.f, 0.f, 0.f, 0.f};
#pragma unroll
  for (int m = 0; m < MS; ++m) {
    float4 pa = *(const float4*)&pacc[(((size_t)m * NB + b) * CO + c) * NPIX + n];
    float4 lv = *(const float4*)&pl[((size_t)m * NB + b) * NPIX + n];
    o.x += pa.x; o.y += pa.y; o.z += pa.z; o.w += pa.w;
    L.x += lv.x; L.y += lv.y; L.z += lv.z; L.w += lv.w;
  }
  size_t xi = ((size_t)b * CO + c) * NPIX + n;
  float4 yv = *(const float4*)&y[xi];
  float s = scv[c], ob = sbv[c];
  float gm = gam[0];
  float4 r;
  r.x = gm * (o.x / L.x) + fmaxf(yv.x * s + ob, 0.f);
  r.y = gm * (o.y / L.y) + fmaxf(yv.y * s + ob, 0.f);
  r.z = gm * (o.z / L.z) + fmaxf(yv.z * s + ob, 0.f);
  r.w = gm * (o.w / L.w) + fmaxf(yv.w * s + ob, 0.f);
  *(float4*)&xout[xi] = r;
}

// ---------------------------------------------------------------------------
// Final: BN apply + ReLU + GAP (float4)
// ---------------------------------------------------------------------------
__global__ __launch_bounds__(256) void bn_relu_gap_k(
    const float* __restrict__ y, const float* __restrict__ scv, const float* __restrict__ sbv,
    float* __restrict__ out, int C) {
  int d = blockIdx.x;
  int b = blockIdx.y;
  int tid = threadIdx.x;
  const float* yr = y + ((size_t)b * C + d) * NPIX;
  float sc = scv[d], sb = sbv[d];
  float s = 0.f;
  for (int n4 = tid; n4 < NPIX / 4; n4 += 256) {
    float4 v = *(const float4*)&yr[n4 * 4];
    s += fmaxf(v.x * sc + sb, 0.f) + fmaxf(v.y * sc + sb, 0.f) +
         fmaxf(v.z * sc + sb, 0.f) + fmaxf(v.w * sc + sb, 0.f);
  }
  __shared__ float sh[256];
  sh[tid] = s;
  __syncthreads();
  for (int st = 128; st > 0; st >>= 1) {
    if (tid < st) sh[tid] += sh[tid + st];
    __syncthreads();
  }
  if (tid == 0) out[(size_t)b * C + d] = sh[0] * (1.f / NPIX);
}

// ---------------------------------------------------------------------------
// Host side
// ---------------------------------------------------------------------------
extern "C" void kernel_launch(void* const* d_in, const int* in_sizes, int n_in,
                              void* d_out, int out_size, void* d_ws, size_t ws_size,
                              hipStream_t stream) {
  const float* x    = (const float*)d_in[0];
  const float* wfin = (const float*)d_in[34];
  const float* bnfg = (const float*)d_in[35];
  const float* bnfb = (const float*)d_in[36];

  float* ws = (float*)d_ws;
  size_t off = 0;
  float* y    = ws + off; off += (size_t)NB * 512 * NPIX;
  float* xo   = ws + off; off += (size_t)NB * 96 * NPIX;
  __hip_bfloat16* fqT = (__hip_bfloat16*)(ws + off); off += (size_t)NB * NPIX * 16;
  __hip_bfloat16* gqT = (__hip_bfloat16*)(ws + off); off += (size_t)NB * NPIX * 16;
  __hip_bfloat16* hq  = (__hip_bfloat16*)(ws + off); off += (size_t)NB * 48 * NPIX;
  float* scv  = ws + off; off += 512;
  float* sbv  = ws + off; off += 512;
  float* psum = ws + off; off += 512 * 8;
  float* psq  = ws + off; off += 512 * 8;
  float* pl   = ws + off; off += (size_t)MS * NB * NPIX;
  float* pacc = ws + off; off += (size_t)MS * NB * NPIX * 96;

  const int Ci_arr[3] = {3, 32, 64};
  const int Co_arr[3] = {32, 64, 96};
  const float* cur = x;
  for (int i = 0; i < 3; ++i) {
    const float* const* p = (const float* const*)(d_in + 1 + i * 11);
    const float* w     = p[0];
    const float* bconv = p[1];
    const float* bg    = p[2];
    const float* bbeta = p[3];
    const float* awf   = p[4];
    const float* abf   = p[5];
    const float* awg   = p[6];
    const float* abg   = p[7];
    const float* awh   = p[8];
    const float* abh   = p[9];
    const float* gam   = p[10];
    int Ci = Ci_arr[i], Co = Co_arr[i];

    conv_stats_k<4><<<dim3(4, Co / 4, NB), 256, 0, stream>>>(cur, w, bconv, y, psum, psq, Ci, Co);
    bn_finalize_k<<<(Co + 255) / 256, 256, 0, stream>>>(psum, psq, bg, bbeta, scv, sbv, Co);

    if (i == 0)      fg_convT_k<4><<<dim3(NPIX / 256, NB), 256, 0, stream>>>(y, scv, sbv, awf, abf, awg, abg, fqT, gqT, Co);
    else if (i == 1) fg_convT_k<8><<<dim3(NPIX / 256, NB), 256, 0, stream>>>(y, scv, sbv, awf, abf, awg, abg, fqT, gqT, Co);
    else             fg_convT_k<12><<<dim3(NPIX / 256, NB), 256, 0, stream>>>(y, scv, sbv, awf, abf, awg, abg, fqT, gqT, Co);

    conv_bf16_k<<<dim3(4, Co / 4, NB), 256, 0, stream>>>(y, scv, sbv, awh, abh, hq, Co, Co);

    dim3 ag(NPIX / QB, MS, NB);
    if (Co == 32) {
      attn_mfma_k<32><<<ag, 256, 0, stream>>>(fqT, gqT, hq, pacc, pl);
      attn_combine2_k<32><<<(NB * 32 * NPIX) / 1024, 256, 0, stream>>>(pacc, pl, y, scv, sbv, gam, xo);
    } else if (Co == 64) {
      attn_mfma_k<64><<<ag, 256, 0, stream>>>(fqT, gqT, hq, pacc, pl);
      attn_combine2_k<64><<<(NB * 64 * NPIX) / 1024, 256, 0, stream>>>(pacc, pl, y, scv, sbv, gam, xo);
    } else {
      attn_mfma_k<96><<<ag, 256, 0, stream>>>(fqT, gqT, hq, pacc, pl);
      attn_combine2_k<96><<<(NB * 96 * NPIX) / 1024, 256, 0, stream>>>(pacc, pl, y, scv, sbv, gam, xo);
    }
    cur = xo;
  }

  // final: conv(96->512, no bias) + stats, finalize, BN+ReLU+GAP
  conv_stats_k<16><<<dim3(4, 512 / 16, NB), 256, 0, stream>>>(cur, wfin, nullptr, y, psum, psq, 96, 512);
  bn_finalize_k<<<2, 256, 0, stream>>>(psum, psq, bnfg, bnfb, scv, sbv, 512);
  bn_relu_gap_k<<<dim3(512, NB), 256, 0, stream>>>(y, scv, sbv, (float*)d_out, 512);
}

// Round 6
// 231.951 us; speedup vs baseline: 1.2357x; 1.2357x over previous
//
#include <hip/hip_runtime.h>
#include <hip/hip_bf16.h>

constexpr int NPIX = 4096;   // H*W
constexpr int NB   = 2;      // batch
constexpr int MS   = 2;      // m-split for attention
constexpr int QB   = 32;     // queries per attention block
constexpr int TM   = 64;     // m per wave-iteration
constexpr int PPITCH = 72;   // P_lds row pitch (bf16): 2-way bank alias only (free)
constexpr int NPART  = 16;   // BN partials per channel (XB*NB with PX=2)

typedef __attribute__((ext_vector_type(8))) short bf16x8;
typedef __attribute__((ext_vector_type(4))) float f32x4;

// ---------------------------------------------------------------------------
// conv1x1 fp32 + fused BN partial stats.
// CPT output channels x PX pixels per thread. grid = (NPIX/(256*PX), Co/CPT, NB).
// Occupancy-first: PX=2 keeps block count high (stage convs are latency-bound).
// ---------------------------------------------------------------------------
template <int CPT, int PX>
__global__ __launch_bounds__(256) void conv_stats_k(
    const float* __restrict__ x, const float* __restrict__ w,
    const float* __restrict__ bias, float* __restrict__ y,
    float* __restrict__ psum, float* __restrict__ psq, int Ci, int Co) {
  constexpr int XB = NPIX / (256 * PX);
  const int t  = threadIdx.x;
  const int n  = (blockIdx.x * 256 + t) * PX;
  const int d0 = blockIdx.y * CPT;
  const int b  = blockIdx.z;
  float a[CPT][PX];
#pragma unroll
  for (int j = 0; j < CPT; ++j) {
    float bv = bias ? bias[d0 + j] : 0.f;
#pragma unroll
    for (int p = 0; p < PX; ++p) a[j][p] = bv;
  }
  const float* xb = x + ((size_t)b * Ci) * NPIX + n;
  const float* wr = w + d0;
#pragma unroll 2
  for (int c = 0; c < Ci; ++c) {
    float xv[PX];
    if constexpr (PX == 2) *(float2*)xv = *(const float2*)(xb + (size_t)c * NPIX);
    else                   *(float4*)xv = *(const float4*)(xb + (size_t)c * NPIX);
#pragma unroll
    for (int j = 0; j < CPT; ++j) {
      float wj = wr[j];
#pragma unroll
      for (int p = 0; p < PX; ++p) a[j][p] += xv[p] * wj;
    }
    wr += Co;
  }
  float* yb = y + ((size_t)b * Co + d0) * NPIX + n;
#pragma unroll
  for (int j = 0; j < CPT; ++j) {
    if constexpr (PX == 2) *(float2*)(yb + (size_t)j * NPIX) = *(float2*)a[j];
    else                   *(float4*)(yb + (size_t)j * NPIX) = *(float4*)a[j];
  }

  float s[CPT], s2[CPT];
#pragma unroll
  for (int j = 0; j < CPT; ++j) {
    s[j] = 0.f; s2[j] = 0.f;
#pragma unroll
    for (int p = 0; p < PX; ++p) { s[j] += a[j][p]; s2[j] += a[j][p] * a[j][p]; }
  }
#pragma unroll
  for (int j = 0; j < CPT; ++j) {
    for (int d = 1; d < 64; d <<= 1) {
      s[j]  += __shfl_xor(s[j], d);
      s2[j] += __shfl_xor(s2[j], d);
    }
  }
  __shared__ float shA[4][CPT];
  __shared__ float shB[4][CPT];
  const int wave = t >> 6, lane = t & 63;
  if (lane == 0) {
#pragma unroll
    for (int j = 0; j < CPT; ++j) { shA[wave][j] = s[j]; shB[wave][j] = s2[j]; }
  }
  __syncthreads();
  if (t < CPT) {
    const int p = b * XB + blockIdx.x;   // NPART partials per channel
    psum[(size_t)(d0 + t) * NPART + p] = (shA[0][t] + shA[1][t]) + (shA[2][t] + shA[3][t]);
    psq [(size_t)(d0 + t) * NPART + p] = (shB[0][t] + shB[1][t]) + (shB[2][t] + shB[3][t]);
  }
}

// ---------------------------------------------------------------------------
// BN finalize: per-channel fused affine sc = rstd*g, sb = bb - mean*sc
// ---------------------------------------------------------------------------
__global__ __launch_bounds__(256) void bn_finalize_k(
    const float* __restrict__ psum, const float* __restrict__ psq,
    const float* __restrict__ g, const float* __restrict__ bb,
    float* __restrict__ sc, float* __restrict__ sb, int C) {
  int c = blockIdx.x * 256 + threadIdx.x;
  if (c >= C) return;
  float s = 0.f, s2 = 0.f;
#pragma unroll
  for (int p = 0; p < NPART; ++p) { s += psum[(size_t)c * NPART + p]; s2 += psq[(size_t)c * NPART + p]; }
  const float inv = 1.f / (NB * NPIX);
  float m = s * inv;
  float var = s2 * inv - m * m;
  float r = rsqrtf(var + 1e-5f) * g[c];
  sc[c] = r;
  sb[c] = bb[c] - m * r;
}

// ---------------------------------------------------------------------------
// f & g convs fused, BN+ReLU applied on the fly from y.
// Output transposed + channel-padded to 32: [B][N][32] bf16.
// ---------------------------------------------------------------------------
template <int CF>
__global__ __launch_bounds__(256) void fg_convT_k(
    const float* __restrict__ y, const float* __restrict__ scv, const float* __restrict__ sbv,
    const float* __restrict__ wf, const float* __restrict__ bfv,
    const float* __restrict__ wg, const float* __restrict__ bgv,
    __hip_bfloat16* __restrict__ fqT, __hip_bfloat16* __restrict__ gqT, int Ci) {
  int n = blockIdx.x * 256 + threadIdx.x;
  int b = blockIdx.y;
  float fa[CF], ga[CF];
#pragma unroll
  for (int j = 0; j < CF; ++j) { fa[j] = bfv[j]; ga[j] = bgv[j]; }
  const float* xb = y + ((size_t)b * Ci) * NPIX + n;
  for (int ci = 0; ci < Ci; ci += 8) {
    float xr[8];
#pragma unroll
    for (int k = 0; k < 8; ++k)
      xr[k] = fmaxf(xb[(size_t)(ci + k) * NPIX] * scv[ci + k] + sbv[ci + k], 0.f);
#pragma unroll
    for (int j = 0; j < CF; ++j) {
      float fs = 0.f, gs = 0.f;
#pragma unroll
      for (int k = 0; k < 8; ++k) {
        fs += xr[k] * wf[(size_t)(ci + k) * CF + j];
        gs += xr[k] * wg[(size_t)(ci + k) * CF + j];
      }
      fa[j] += fs; ga[j] += gs;
    }
  }
  __align__(16) __hip_bfloat16 of[32];
  __align__(16) __hip_bfloat16 og[32];
#pragma unroll
  for (int j = 0; j < 32; ++j) {
    of[j] = __float2bfloat16(j < CF ? fa[j] : 0.f);
    og[j] = __float2bfloat16(j < CF ? ga[j] : 0.f);
  }
  uint4* df = (uint4*)(fqT + ((size_t)b * NPIX + n) * 32);
  uint4* dg = (uint4*)(gqT + ((size_t)b * NPIX + n) * 32);
#pragma unroll
  for (int k = 0; k < 4; ++k) { df[k] = ((uint4*)of)[k]; dg[k] = ((uint4*)og)[k]; }
}

// ---------------------------------------------------------------------------
// h conv -> bf16, BN+ReLU on the fly. 2 channels x 2 pixels per thread.
// grid = (8, Co/2, NB).
// ---------------------------------------------------------------------------
__global__ __launch_bounds__(256) void conv_bf16_k(
    const float* __restrict__ y, const float* __restrict__ scv, const float* __restrict__ sbv,
    const float* __restrict__ w, const float* __restrict__ bias,
    __hip_bfloat16* __restrict__ out, int Ci, int Co) {
  int n  = (blockIdx.x * 256 + threadIdx.x) * 2;
  int d0 = blockIdx.y * 2;
  int b  = blockIdx.z;
  float2 a0 = {bias[d0], bias[d0]};
  float2 a1 = {bias[d0 + 1], bias[d0 + 1]};
  const float* xb = y + ((size_t)b * Ci) * NPIX + n;
  const float* wr = w + d0;
#pragma unroll 4
  for (int c = 0; c < Ci; ++c) {
    float2 xv = *(const float2*)(xb + (size_t)c * NPIX);
    float s = scv[c], o = sbv[c];
    xv.x = fmaxf(xv.x * s + o, 0.f);
    xv.y = fmaxf(xv.y * s + o, 0.f);
    float w0 = wr[0], w1 = wr[1];
    a0.x += xv.x * w0; a0.y += xv.y * w0;
    a1.x += xv.x * w1; a1.y += xv.y * w1;
    wr += Co;
  }
  __hip_bfloat16* yb = out + ((size_t)b * Co + d0) * NPIX + n;
  auto st2 = [](__hip_bfloat16* p, float2 v) {
    __hip_bfloat162 t;
    t.x = __float2bfloat16(v.x); t.y = __float2bfloat16(v.y);
    *(unsigned*)p = *(unsigned*)&t;
  };
  st2(yb, a0);
  st2(yb + NPIX, a1);
}

// ---------------------------------------------------------------------------
// MFMA flash attention partial. pacc layout [MS][B][CO][N].
// ---------------------------------------------------------------------------
template <int CO>
__global__ __launch_bounds__(256, 2) void attn_mfma_k(
    const __hip_bfloat16* __restrict__ fqT, const __hip_bfloat16* __restrict__ gqT,
    const __hip_bfloat16* __restrict__ hq,
    float* __restrict__ pacc, float* __restrict__ pl) {
  constexpr int CSUB   = CO / 16;
  constexpr int OPITCH = CO + 1;
  constexpr int PBYTES = 4 * QB * PPITCH * 2;
  constexpr int OBYTES = 4 * QB * OPITCH * 4;
  constexpr int SBYTES = PBYTES > OBYTES ? PBYTES : OBYTES;
  __shared__ __align__(16) char smem[SBYTES];
  __shared__ float l_red[4][QB];
  unsigned short* Pw = (unsigned short*)smem;
  float* Ored = (float*)smem;

  const int t = threadIdx.x;
  const int wave = t >> 6, lane = t & 63, lq = lane & 15, lg = lane >> 4;
  const int qblk = blockIdx.x, ms = blockIdx.y, b = blockIdx.z;
  const int q0 = qblk * QB;

  bf16x8 ff[2];
#pragma unroll
  for (int qs = 0; qs < 2; ++qs)
    ff[qs] = *reinterpret_cast<const bf16x8*>(
        fqT + (((size_t)b * NPIX + q0 + qs * 16 + lq) << 5) + lg * 8);

  f32x4 acc[2][CSUB];
#pragma unroll
  for (int qs = 0; qs < 2; ++qs)
#pragma unroll
    for (int cs = 0; cs < CSUB; ++cs) acc[qs][cs] = f32x4{0.f, 0.f, 0.f, 0.f};
  float ls[2] = {0.f, 0.f};

  unsigned short* Pmy = Pw + wave * QB * PPITCH;
  const __hip_bfloat16* hbase = hq + ((size_t)b * CO + lq) * NPIX + lg * 8;

  const int mbeg = ms * (NPIX / MS) + wave * TM;
  const int mend = (ms + 1) * (NPIX / MS);
  for (int mt = mbeg; mt < mend; mt += 4 * TM) {
#pragma unroll
    for (int msub = 0; msub < 4; ++msub) {
      bf16x8 ga = *reinterpret_cast<const bf16x8*>(
          gqT + (((size_t)b * NPIX + mt + msub * 16 + lq) << 5) + lg * 8);
#pragma unroll
      for (int qs = 0; qs < 2; ++qs) {
        f32x4 z = {0.f, 0.f, 0.f, 0.f};
        f32x4 S = __builtin_amdgcn_mfma_f32_16x16x32_bf16(ga, ff[qs], z, 0, 0, 0);
        float p0 = __expf(fminf(S[0], 60.f));
        float p1 = __expf(fminf(S[1], 60.f));
        float p2 = __expf(fminf(S[2], 60.f));
        float p3 = __expf(fminf(S[3], 60.f));
        ls[qs] += (p0 + p1) + (p2 + p3);
        __hip_bfloat162 t0, t1;
        t0.x = __float2bfloat16(p0); t0.y = __float2bfloat16(p1);
        t1.x = __float2bfloat16(p2); t1.y = __float2bfloat16(p3);
        uint2 wv;
        wv.x = *(unsigned*)&t0; wv.y = *(unsigned*)&t1;
        *(uint2*)(Pmy + (qs * 16 + lq) * PPITCH + msub * 16 + lg * 4) = wv;
      }
    }
#pragma unroll
    for (int kc = 0; kc < 2; ++kc) {
      bf16x8 pa[2];
#pragma unroll
      for (int qs = 0; qs < 2; ++qs)
        pa[qs] = *reinterpret_cast<const bf16x8*>(
            Pmy + (qs * 16 + lq) * PPITCH + kc * 32 + lg * 8);
      const __hip_bfloat16* hp = hbase + mt + kc * 32;
#pragma unroll
      for (int cs = 0; cs < CSUB; ++cs) {
        bf16x8 hv = *reinterpret_cast<const bf16x8*>(hp + (size_t)cs * 16 * NPIX);
#pragma unroll
        for (int qs = 0; qs < 2; ++qs)
          acc[qs][cs] = __builtin_amdgcn_mfma_f32_16x16x32_bf16(pa[qs], hv, acc[qs][cs], 0, 0, 0);
      }
    }
  }

#pragma unroll
  for (int qs = 0; qs < 2; ++qs) {
    float l = ls[qs];
    l += __shfl_xor(l, 16);
    l += __shfl_xor(l, 32);
    ls[qs] = l;
  }

  __syncthreads();
  if (lane < 16) { l_red[wave][lq] = ls[0]; l_red[wave][16 + lq] = ls[1]; }
#pragma unroll
  for (int qs = 0; qs < 2; ++qs)
#pragma unroll
    for (int cs = 0; cs < CSUB; ++cs)
#pragma unroll
      for (int r = 0; r < 4; ++r)
        Ored[((size_t)wave * QB + qs * 16 + 4 * lg + r) * OPITCH + cs * 16 + lq] = acc[qs][cs][r];
  __syncthreads();

  const size_t obase = (((size_t)ms * NB + b) * CO) * NPIX + q0;
  for (int e = t; e < QB * CO; e += 256) {
    int c = e >> 5;
    int q = e & 31;
    float o = Ored[((size_t)0 * QB + q) * OPITCH + c] + Ored[((size_t)1 * QB + q) * OPITCH + c] +
              Ored[((size_t)2 * QB + q) * OPITCH + c] + Ored[((size_t)3 * QB + q) * OPITCH + c];
    pacc[obase + (size_t)c * NPIX + q] = o;
  }
  if (t < QB) {
    pl[((size_t)ms * NB + b) * NPIX + q0 + t] =
        l_red[0][t] + l_red[1][t] + l_red[2][t] + l_red[3][t];
  }
}

// ---------------------------------------------------------------------------
// Attention combine: merge m-splits, normalize, gamma + residual (BN+ReLU of y
// applied on the fly). float4 streaming.
// ---------------------------------------------------------------------------
template <int CO>
__global__ __launch_bounds__(256) void attn_combine2_k(
    const float* __restrict__ pacc, const float* __restrict__ pl,
    const float* __restrict__ y, const float* __restrict__ scv, const float* __restrict__ sbv,
    const float* __restrict__ gam, float* __restrict__ xout) {
  int i4 = blockIdx.x * 256 + threadIdx.x;   // over NB*CO*NPIX/4
  int n  = (i4 & 1023) * 4;
  int bc = i4 >> 10;
  int b  = bc / CO, c = bc - b * CO;
  float4 o = {0.f, 0.f, 0.f, 0.f};
  float4 L = {0.f, 0.f, 0.f, 0.f};
#pragma unroll
  for (int m = 0; m < MS; ++m) {
    float4 pa = *(const float4*)&pacc[(((size_t)m * NB + b) * CO + c) * NPIX + n];
    float4 lv = *(const float4*)&pl[((size_t)m * NB + b) * NPIX + n];
    o.x += pa.x; o.y += pa.y; o.z += pa.z; o.w += pa.w;
    L.x += lv.x; L.y += lv.y; L.z += lv.z; L.w += lv.w;
  }
  size_t xi = ((size_t)b * CO + c) * NPIX + n;
  float4 yv = *(const float4*)&y[xi];
  float s = scv[c], ob = sbv[c];
  float gm = gam[0];
  float4 r;
  r.x = gm * (o.x / L.x) + fmaxf(yv.x * s + ob, 0.f);
  r.y = gm * (o.y / L.y) + fmaxf(yv.y * s + ob, 0.f);
  r.z = gm * (o.z / L.z) + fmaxf(yv.z * s + ob, 0.f);
  r.w = gm * (o.w / L.w) + fmaxf(yv.w * s + ob, 0.f);
  *(float4*)&xout[xi] = r;
}

// ---------------------------------------------------------------------------
// Final: BN apply + ReLU + GAP (float4)
// ---------------------------------------------------------------------------
__global__ __launch_bounds__(256) void bn_relu_gap_k(
    const float* __restrict__ y, const float* __restrict__ scv, const float* __restrict__ sbv,
    float* __restrict__ out, int C) {
  int d = blockIdx.x;
  int b = blockIdx.y;
  int tid = threadIdx.x;
  const float* yr = y + ((size_t)b * C + d) * NPIX;
  float sc = scv[d], sb = sbv[d];
  float s = 0.f;
  for (int n4 = tid; n4 < NPIX / 4; n4 += 256) {
    float4 v = *(const float4*)&yr[n4 * 4];
    s += fmaxf(v.x * sc + sb, 0.f) + fmaxf(v.y * sc + sb, 0.f) +
         fmaxf(v.z * sc + sb, 0.f) + fmaxf(v.w * sc + sb, 0.f);
  }
  __shared__ float sh[256];
  sh[tid] = s;
  __syncthreads();
  for (int st = 128; st > 0; st >>= 1) {
    if (tid < st) sh[tid] += sh[tid + st];
    __syncthreads();
  }
  if (tid == 0) out[(size_t)b * C + d] = sh[0] * (1.f / NPIX);
}

// ---------------------------------------------------------------------------
// Host side
// ---------------------------------------------------------------------------
extern "C" void kernel_launch(void* const* d_in, const int* in_sizes, int n_in,
                              void* d_out, int out_size, void* d_ws, size_t ws_size,
                              hipStream_t stream) {
  const float* x    = (const float*)d_in[0];
  const float* wfin = (const float*)d_in[34];
  const float* bnfg = (const float*)d_in[35];
  const float* bnfb = (const float*)d_in[36];

  float* ws = (float*)d_ws;
  size_t off = 0;
  float* y    = ws + off; off += (size_t)NB * 512 * NPIX;
  float* xo   = ws + off; off += (size_t)NB * 96 * NPIX;
  __hip_bfloat16* fqT = (__hip_bfloat16*)(ws + off); off += (size_t)NB * NPIX * 16;
  __hip_bfloat16* gqT = (__hip_bfloat16*)(ws + off); off += (size_t)NB * NPIX * 16;
  __hip_bfloat16* hq  = (__hip_bfloat16*)(ws + off); off += (size_t)NB * 48 * NPIX;
  float* scv  = ws + off; off += 512;
  float* sbv  = ws + off; off += 512;
  float* psum = ws + off; off += 512 * NPART;
  float* psq  = ws + off; off += 512 * NPART;
  float* pl   = ws + off; off += (size_t)MS * NB * NPIX;
  float* pacc = ws + off; off += (size_t)MS * NB * NPIX * 96;

  const int Ci_arr[3] = {3, 32, 64};
  const int Co_arr[3] = {32, 64, 96};
  const float* cur = x;
  for (int i = 0; i < 3; ++i) {
    const float* const* p = (const float* const*)(d_in + 1 + i * 11);
    const float* w     = p[0];
    const float* bconv = p[1];
    const float* bg    = p[2];
    const float* bbeta = p[3];
    const float* awf   = p[4];
    const float* abf   = p[5];
    const float* awg   = p[6];
    const float* abg   = p[7];
    const float* awh   = p[8];
    const float* abh   = p[9];
    const float* gam   = p[10];
    int Ci = Ci_arr[i], Co = Co_arr[i];

    conv_stats_k<2, 2><<<dim3(8, Co / 2, NB), 256, 0, stream>>>(cur, w, bconv, y, psum, psq, Ci, Co);
    bn_finalize_k<<<(Co + 255) / 256, 256, 0, stream>>>(psum, psq, bg, bbeta, scv, sbv, Co);

    if (i == 0)      fg_convT_k<4><<<dim3(NPIX / 256, NB), 256, 0, stream>>>(y, scv, sbv, awf, abf, awg, abg, fqT, gqT, Co);
    else if (i == 1) fg_convT_k<8><<<dim3(NPIX / 256, NB), 256, 0, stream>>>(y, scv, sbv, awf, abf, awg, abg, fqT, gqT, Co);
    else             fg_convT_k<12><<<dim3(NPIX / 256, NB), 256, 0, stream>>>(y, scv, sbv, awf, abf, awg, abg, fqT, gqT, Co);

    conv_bf16_k<<<dim3(8, Co / 2, NB), 256, 0, stream>>>(y, scv, sbv, awh, abh, hq, Co, Co);

    dim3 ag(NPIX / QB, MS, NB);
    if (Co == 32) {
      attn_mfma_k<32><<<ag, 256, 0, stream>>>(fqT, gqT, hq, pacc, pl);
      attn_combine2_k<32><<<(NB * 32 * NPIX) / 1024, 256, 0, stream>>>(pacc, pl, y, scv, sbv, gam, xo);
    } else if (Co == 64) {
      attn_mfma_k<64><<<ag, 256, 0, stream>>>(fqT, gqT, hq, pacc, pl);
      attn_combine2_k<64><<<(NB * 64 * NPIX) / 1024, 256, 0, stream>>>(pacc, pl, y, scv, sbv, gam, xo);
    } else {
      attn_mfma_k<96><<<ag, 256, 0, stream>>>(fqT, gqT, hq, pacc, pl);
      attn_combine2_k<96><<<(NB * 96 * NPIX) / 1024, 256, 0, stream>>>(pacc, pl, y, scv, sbv, gam, xo);
    }
    cur = xo;
  }

  // final: conv(96->512, no bias) + stats, finalize, BN+ReLU+GAP
  conv_stats_k<8, 2><<<dim3(8, 512 / 8, NB), 256, 0, stream>>>(cur, wfin, nullptr, y, psum, psq, 96, 512);
  bn_finalize_k<<<2, 256, 0, stream>>>(psum, psq, bnfg, bnfb, scv, sbv, 512);
  bn_relu_gap_k<<<dim3(512, NB), 256, 0, stream>>>(y, scv, sbv, (float*)d_out, 512);
}